// Round 19
// baseline (161.070 us; speedup 1.0000x reference)
//
#include <hip/hip_runtime.h>
#include <hip/hip_bf16.h>
#include <cstdint>

#define FEAT    128
#define NRBF    20
#define NATOMS  8192
#define NEDGES  262144
#define NGRAPH  128
#define APG     64
#define PI_F    3.14159265358979323846f
#define CUTOFF_F 5.0f
#define QTUS    ((size_t)NATOMS * 32 * 6)   // ushorts per PV quarter-table (3.15 MB)
#define APW     2                           // atoms per wave (edge kernel)

typedef unsigned int uint_t;
typedef unsigned short ushort_t;
typedef __attribute__((ext_vector_type(4))) float f32x4;
typedef __attribute__((ext_vector_type(4))) short short4v;
typedef __attribute__((ext_vector_type(8))) short short8;
struct U3 { uint_t x, y, z; };   // 12 B -> global_load_dwordx3

__device__ __forceinline__ float bflo(uint_t u) { return __uint_as_float(u << 16); }
__device__ __forceinline__ float bfhi(uint_t u) { return __uint_as_float(u & 0xffff0000u); }
__device__ __forceinline__ ushort_t f2bf(float f) {
  uint_t u = __float_as_uint(f);
  return (ushort_t)((u + 0x7fffu + ((u >> 16) & 1u)) >> 16);
}
__device__ __forceinline__ uint_t pack2(float lo, float hi) {
  return (uint_t)f2bf(lo) | ((uint_t)f2bf(hi) << 16);
}

// ---------------------------------------------------------------- prep (+hist fused)
__device__ __forceinline__ ushort_t swz_elem(const float* __restrict__ W, int N,
                                             int NT, int i) {
  int jj = i & 7, lane = (i >> 3) & 63, tile = i >> 9;
  int ks = tile / NT, ctg = tile - ks * NT;
  int g = lane >> 4, q = lane & 15;
  int k = 32 * ks + 4 * g + (jj & 3) + 16 * (jj >> 2);
  int c = 16 * ctg + q;
  return f2bf(W[(size_t)k * N + c]);
}

__global__ void prep_kernel(const float* __restrict__ v_j, const float* __restrict__ W1,
                            const float* __restrict__ W2, const float* __restrict__ Wd,
                            const float* __restrict__ Wr, const float* __restrict__ br,
                            const int* __restrict__ nbrs,
                            ushort_t* __restrict__ PV, ushort_t* __restrict__ w1s,
                            ushort_t* __restrict__ w2s, ushort_t* __restrict__ wds,
                            ushort_t* __restrict__ wrs, int* __restrict__ counts) {
  int i = blockIdx.x * 256 + threadIdx.x;
  if (i < NATOMS * FEAT) {                 // i = j*128 + f
    int j = i >> 7, f = i & 127;
    int tbl = f >> 5, fl = f & 31;
    const float* vp = v_j + (size_t)i * 3; // v_j[j][f][0..2]
    uint_t* o = reinterpret_cast<uint_t*>(PV + (size_t)tbl * QTUS + ((size_t)j * 32 + fl) * 6);
    o[0] = 0u;                     // p0,p1 (gemm fills)
    o[1] = pack2(0.f, vp[0]);      // p2,v0
    o[2] = pack2(vp[1], vp[2]);    // v1,v2
    return;
  }
  i -= NATOMS * FEAT;
  if (i < 16384) { w1s[i] = swz_elem(W1, 128, 8, i); return; }
  i -= 16384;
  if (i < 49152) { w2s[i] = swz_elem(W2, 384, 24, i); return; }
  i -= 49152;
  if (i < 49152) { wds[i] = swz_elem(Wd, 384, 24, i); return; }
  i -= 49152;
  if (i < 12288) {                 // Wr/br frag-order: 24 tiles, k=20 row is br
    int jj = i & 7, lane = (i >> 3) & 63, ct = i >> 9;
    int g = lane >> 4, q = lane & 15;
    int k = 4 * g + (jj & 3) + 16 * (jj >> 2);
    int f = 16 * ct + q;
    float v = (k < NRBF) ? Wr[k * 384 + f] : (k == NRBF ? br[f] : 0.f);
    wrs[i] = f2bf(v);
    return;
  }
  i -= 12288;
  if (i < NEDGES) atomicAdd(&counts[nbrs[2 * i]], 1);   // fused histogram
}

// ---------------------------------------------------------------- big GEMM
// Grid (128, 6): per block stage s_j tile once; emit qkv slice y AND phi slice y
// (h recomputed into Buf). Fragment maps HW-verified (rounds 3-18).
__global__ __launch_bounds__(256) void gemm_big(
    const float* __restrict__ s_j, const ushort_t* __restrict__ w1s,
    const float* __restrict__ b1, const ushort_t* __restrict__ w2s,
    const float* __restrict__ b2, const ushort_t* __restrict__ wds,
    const float* __restrict__ bd, ushort_t* __restrict__ PV,
    float* __restrict__ Qf, ushort_t* __restrict__ kvbf) {
  __shared__ ushort_t Buf[64][136];
  const int t = threadIdx.x;
  const int r0 = blockIdx.x * 64;
  const int y = blockIdx.y;                // 0..5
  const int w = t >> 6, l = t & 63, g = l >> 4, q = l & 15;

  for (int i = t; i < 64 * 32; i += 256) {
    int r = i >> 5, k4 = i & 31;
    float4 v = *reinterpret_cast<const float4*>(s_j + (size_t)(r0 + r) * 128 + 4 * k4);
    ushort4 o = {f2bf(v.x), f2bf(v.y), f2bf(v.z), f2bf(v.w)};
    *reinterpret_cast<ushort4*>(&Buf[r][4 * k4]) = o;
  }
  __syncthreads();

  short8 afr[4];
  #pragma unroll
  for (int ks = 0; ks < 4; ++ks) {
    const ushort_t* ap = &Buf[16 * w + q][32 * ks + 4 * g];
    short4v alo = *reinterpret_cast<const short4v*>(ap);
    short4v ahi = *reinterpret_cast<const short4v*>(ap + 16);
    afr[ks] = short8{alo[0], alo[1], alo[2], alo[3], ahi[0], ahi[1], ahi[2], ahi[3]};
  }
  __syncthreads();   // all Buf reads done before the h overwrite below

  // ---- qkv slice y
  #pragma unroll
  for (int ct = 0; ct < 4; ++ct) {
    f32x4 acc = {};
    #pragma unroll
    for (int ks = 0; ks < 4; ++ks) {
      short8 bf = *reinterpret_cast<const short8*>(
          wds + ((size_t)(ks * 24 + y * 4 + ct) * 64 + l) * 8);
      acc = __builtin_amdgcn_mfma_f32_16x16x32_bf16(afr[ks], bf, acc, 0, 0, 0);
    }
    int col = y * 64 + 16 * ct + q;
    float bb = bd[col];
    #pragma unroll
    for (int r = 0; r < 4; ++r) {
      float o = acc[r] + bb;
      int row = r0 + 16 * w + 4 * g + r;
      if (col < 128) Qf[(size_t)row * 128 + col] = o;
      else           kvbf[(size_t)row * 256 + col - 128] = f2bf(o);
    }
  }

  // ---- h = silu(s@W1+b1) into Buf
  #pragma unroll
  for (int ct = 0; ct < 8; ++ct) {
    f32x4 acc = {};
    #pragma unroll
    for (int ks = 0; ks < 4; ++ks) {
      short8 bf = *reinterpret_cast<const short8*>(
          w1s + ((size_t)(ks * 8 + ct) * 64 + l) * 8);
      acc = __builtin_amdgcn_mfma_f32_16x16x32_bf16(afr[ks], bf, acc, 0, 0, 0);
    }
    float bb = b1[16 * ct + q];
    #pragma unroll
    for (int r = 0; r < 4; ++r) {
      float o = acc[r] + bb;
      o = o / (1.f + __expf(-o));
      Buf[16 * w + 4 * g + r][16 * ct + q] = f2bf(o);
    }
  }
  __syncthreads();

  // ---- phi slice y from Buf
  short8 hfr[4];
  #pragma unroll
  for (int ks = 0; ks < 4; ++ks) {
    const ushort_t* ap = &Buf[16 * w + q][32 * ks + 4 * g];
    short4v alo = *reinterpret_cast<const short4v*>(ap);
    short4v ahi = *reinterpret_cast<const short4v*>(ap + 16);
    hfr[ks] = short8{alo[0], alo[1], alo[2], alo[3], ahi[0], ahi[1], ahi[2], ahi[3]};
  }
  #pragma unroll
  for (int ct = 0; ct < 4; ++ct) {
    f32x4 acc = {};
    #pragma unroll
    for (int ks = 0; ks < 4; ++ks) {
      short8 bf = *reinterpret_cast<const short8*>(
          w2s + ((size_t)(ks * 24 + y * 4 + ct) * 64 + l) * 8);
      acc = __builtin_amdgcn_mfma_f32_16x16x32_bf16(hfr[ks], bf, acc, 0, 0, 0);
    }
    int col = y * 64 + 16 * ct + q;
    float bb = b2[col];
    int f = col & 127, s = col >> 7;
    int tbl = f >> 5, fl = f & 31;
    #pragma unroll
    for (int r = 0; r < 4; ++r) {
      float o = acc[r] + bb;
      int row = r0 + 16 * w + 4 * g + r;
      PV[(size_t)tbl * QTUS + ((size_t)row * 32 + fl) * 6 + s] = f2bf(o);
    }
  }
}

// ---------------------------------------------------------------- sort helpers
__global__ __launch_bounds__(1024) void scan_kernel(
    const int* __restrict__ counts, int* __restrict__ offs, int* __restrict__ cursor) {
  __shared__ int part[1024];
  const int t = threadIdx.x;
  int local[8];
  int s = 0;
  #pragma unroll
  for (int i = 0; i < 8; ++i) { local[i] = counts[t * 8 + i]; s += local[i]; }
  part[t] = s;
  __syncthreads();
  for (int off = 1; off < 1024; off <<= 1) {
    int v = part[t];
    int add = (t >= off) ? part[t - off] : 0;
    __syncthreads();
    part[t] = v + add;
    __syncthreads();
  }
  int excl = part[t] - s;
  #pragma unroll
  for (int i = 0; i < 8; ++i) {
    offs[t * 8 + i] = excl;
    cursor[t * 8 + i] = excl;
    excl += local[i];
  }
  if (t == 1023) offs[NATOMS] = excl;
}

// Pre-joined 16 B edge records {j, x, y, z} in sorted (dest-atom) order.
__global__ void scatter_kernel(const int* __restrict__ nbrs, const float* __restrict__ r_ij,
                               int* __restrict__ cursor, uint4* __restrict__ erec) {
  int e = blockIdx.x * blockDim.x + threadIdx.x;
  if (e < NEDGES) {
    int2 nb = *reinterpret_cast<const int2*>(nbrs + 2 * e);
    int pos = atomicAdd(&cursor[nb.x], 1);
    const float* rp = r_ij + 3 * e;
    erec[pos] = make_uint4((uint_t)nb.y, __float_as_uint(rp[0]),
                           __float_as_uint(rp[1]), __float_as_uint(rp[2]));
  }
}

// ---------------------------------------------------------------- edge MFMA v12
// r18 structure + SOFTWARE-PIPELINED PV GATHERS: tile t+1's addresses need only
// j (er.x, no trig), so they are formed and the 8 gathers ISSUED one full tile
// early -- consumption happens ~a full iteration (trig+MFMA+epilogue) later,
// hiding the L2 round-trip that the old issue-and-consume-same-tile loop exposed.
// Trig/u-shuffles stay at consume time (they overlap the in-flight loads).
// Zero LDS; B-frags in registers; qtr = bid&3 keeps the L2-capacity-fit XCD map.
__global__ __launch_bounds__(256) void edge_mfma12(
    const uint4* __restrict__ erec, const int* __restrict__ offs,
    const ushort_t* __restrict__ PV, const ushort_t* __restrict__ wrs,
    float* __restrict__ out_s, float* __restrict__ out_v) {
  const int t = threadIdx.x;
  const int qtr = blockIdx.x & 3;
  const int w = t >> 6, l = t & 63, g = l >> 4, q = l & 15;

  // loop-invariant B-frags: [section][ct]
  short8 Bf[3][2];
  #pragma unroll
  for (int s = 0; s < 3; ++s)
    #pragma unroll
    for (int c = 0; c < 2; ++c)
      Bf[s][c] = *reinterpret_cast<const short8*>(
          wrs + ((size_t)(s * 8 + 2 * qtr + c) * 64 + l) * 8);

  const int a0 = ((blockIdx.x >> 2) * 4 + w) * APW;
  const float c1 = PI_F / CUTOFF_F;
  const char* PVb = reinterpret_cast<const char*>(PV) + (size_t)qtr * QTUS * 2;

  int ai = 0;
  int eb = offs[a0];
  int end = offs[a0 + 1];
  int end_next = offs[a0 + 2];   // a0+2 <= NATOMS always (APW=2)

  // ---- prologue: tile-0 record + addresses + gathers
  uint4 er = make_uint4(0u, 0u, 0u, 0u);
  if (eb + q < end) er = erec[eb + q];
  U3 ld[2][4];
  {
    const char* pb[4];
    #pragma unroll
    for (int r = 0; r < 4; ++r) {
      int jr = __shfl((int)er.x, 4 * g + r, 64);
      pb[r] = PVb + (size_t)jr * 384 + (size_t)q * 12;
    }
    #pragma unroll
    for (int c = 0; c < 2; ++c)
      #pragma unroll
      for (int r = 0; r < 4; ++r)
        ld[c][r] = *reinterpret_cast<const U3*>(pb[r] + (size_t)c * 192);
  }

  float ds0 = 0.f, ds1 = 0.f;
  float dv[2][3] = {};

  for (;;) {
    const bool atom_done = (eb + 16 >= end);
    const bool have_next_atom = (ai + 1 < APW);
    const bool final_tile = atom_done && !have_next_atom;
    const int neb = atom_done ? end : (eb + 16);
    const int nend = atom_done ? (have_next_atom ? end_next : neb) : end;

    // ---- prefetch next record + ISSUE next tile's gathers (wave-uniform guard)
    uint4 ern = make_uint4(0u, 0u, 0u, 0u);
    U3 ldn[2][4];
    if (!final_tile) {
      if (neb + q < nend) ern = erec[neb + q];
      const char* pbn[4];
      #pragma unroll
      for (int r = 0; r < 4; ++r) {
        int jr = __shfl((int)ern.x, 4 * g + r, 64);
        pbn[r] = PVb + (size_t)jr * 384 + (size_t)q * 12;
      }
      #pragma unroll
      for (int c = 0; c < 2; ++c)
        #pragma unroll
        for (int r = 0; r < 4; ++r)
          ldn[c][r] = *reinterpret_cast<const U3*>(pbn[r] + (size_t)c * 192);
    }

    // ---- consume current tile: trig + af + u-shuffles + MFMA + epilogue(ld)
    float ang = 0.f, ie = 0.f, env = 0.f, u0 = 0.f, u1 = 0.f, u2 = 0.f;
    if (eb + q < end) {
      float x = __uint_as_float(er.y), y = __uint_as_float(er.z), z = __uint_as_float(er.w);
      float d = sqrtf(x * x + y * y + z * z);
      float inv = 1.f / d;
      ang = c1 * d;
      env = (d < CUTOFF_F) ? 0.5f * (__cosf(ang) + 1.f) : 0.f;
      ie = inv * env;
      u0 = x * inv; u1 = y * inv; u2 = z * inv;
    }
    float ub[4][3];
    #pragma unroll
    for (int r = 0; r < 4; ++r) {
      int src = 4 * g + r;
      ub[r][0] = __shfl(u0, src, 64);
      ub[r][1] = __shfl(u1, src, 64);
      ub[r][2] = __shfl(u2, src, 64);
    }
    short8 af;
    #pragma unroll
    for (int jj = 0; jj < 8; ++jj) {
      int k = 4 * g + (jj & 3) + 16 * (jj >> 2);
      float v = (k < NRBF) ? ie * __sinf((float)(k + 1) * ang)
                           : (k == NRBF ? env : 0.f);
      af[jj] = (short)f2bf(v);
    }
    #pragma unroll
    for (int c = 0; c < 2; ++c) {
      f32x4 z4 = {0.f, 0.f, 0.f, 0.f};
      f32x4 cs0 = __builtin_amdgcn_mfma_f32_16x16x32_bf16(af, Bf[0][c], z4, 0, 0, 0);
      f32x4 cs1 = __builtin_amdgcn_mfma_f32_16x16x32_bf16(af, Bf[1][c], z4, 0, 0, 0);
      f32x4 cs2 = __builtin_amdgcn_mfma_f32_16x16x32_bf16(af, Bf[2][c], z4, 0, 0, 0);
      #pragma unroll
      for (int r = 0; r < 4; ++r) {
        U3 u = ld[c][r];
        float p0 = bflo(u.x), p1 = bfhi(u.x);
        float p2 = bflo(u.y), v0 = bfhi(u.y);
        float v1 = bflo(u.z), v2 = bfhi(u.z);
        float pw0 = p0 * cs0[r];
        if (c == 0) ds0 += p1 * cs1[r]; else ds1 += p1 * cs1[r];
        float pw2 = p2 * cs2[r];
        dv[c][0] += pw0 * v0 + pw2 * ub[r][0];
        dv[c][1] += pw0 * v1 + pw2 * ub[r][1];
        dv[c][2] += pw0 * v2 + pw2 * ub[r][2];
      }
    }

    // ---- atom boundary: reduce, write, reset accumulators
    if (atom_done) {
      float r0v = ds0, r1v = ds1;
      r0v += __shfl_xor(r0v, 16, 64); r0v += __shfl_xor(r0v, 32, 64);
      r1v += __shfl_xor(r1v, 16, 64); r1v += __shfl_xor(r1v, 32, 64);
      float dvr[2][3];
      #pragma unroll
      for (int c = 0; c < 2; ++c)
        #pragma unroll
        for (int cc = 0; cc < 3; ++cc) {
          float y = dv[c][cc];
          y += __shfl_xor(y, 16, 64); y += __shfl_xor(y, 32, 64);
          dvr[c][cc] = y;
        }
      if (g < 2) {
        int atom = a0 + ai;
        float sv = (g == 0) ? r0v : r1v;
        float d0 = (g == 0) ? dvr[0][0] : dvr[1][0];
        float d1 = (g == 0) ? dvr[0][1] : dvr[1][1];
        float d2 = (g == 0) ? dvr[0][2] : dvr[1][2];
        int f = 32 * qtr + 16 * g + q;
        out_s[(size_t)atom * FEAT + f] = sv;
        float* ov = out_v + (size_t)atom * 384 + (size_t)f * 3;
        ov[0] = d0; ov[1] = d1; ov[2] = d2;
      }
      ds0 = 0.f; ds1 = 0.f;
      #pragma unroll
      for (int c = 0; c < 2; ++c)
        #pragma unroll
        for (int cc = 0; cc < 3; ++cc) dv[c][cc] = 0.f;
      ++ai;
      if (ai == APW) break;
      end = end_next;
    }

    // ---- rotate pipeline state
    er = ern;
    eb = neb;
    #pragma unroll
    for (int c = 0; c < 2; ++c)
      #pragma unroll
      for (int r = 0; r < 4; ++r) ld[c][r] = ldn[c][r];
    if (atom_done) end = (eb < end_next) ? end_next : end_next;  // end already set; keep
  }
}

// ---------------------------------------------------------------- attention
__device__ __forceinline__ float wave_max64(float v) {
  #pragma unroll
  for (int m = 32; m > 0; m >>= 1) v = fmaxf(v, __shfl_xor(v, m, 64));
  return v;
}
__device__ __forceinline__ float wave_sum64(float v) {
  #pragma unroll
  for (int m = 32; m > 0; m >>= 1) v += __shfl_xor(v, m, 64);
  return v;
}
__device__ __forceinline__ float bfus2(ushort_t u) { return __uint_as_float((uint_t)u << 16); }

// 4 blocks per graph (quad = bid&3); each wave handles one group of 4 queries.
__global__ __launch_bounds__(256) void attn_kernel(const float* __restrict__ Qf,
                                                   const ushort_t* __restrict__ kvbf,
                                                   float* __restrict__ out_s) {
  __shared__ float4 Ks4[64 * 32];
  __shared__ float  Vs[64][130];
  __shared__ float  Ps[4][4][64];
  const int b = blockIdx.x >> 2, quad = blockIdx.x & 3;
  const int t = threadIdx.x;
  const float* qbase = Qf + (size_t)b * APG * 128;
  const ushort_t* kvb = kvbf + (size_t)b * APG * 256;

  for (int i = t; i < 64 * 32; i += 256) {
    int a = i >> 5, gg = i & 31;
    ushort4 k4 = *reinterpret_cast<const ushort4*>(kvb + a * 256 + 4 * gg);
    float4 kf = {bfus2(k4.x), bfus2(k4.y), bfus2(k4.z), bfus2(k4.w)};
    Ks4[a * 32 + (gg ^ (a & 7))] = kf;
  }
  for (int i = t; i < 64 * 32; i += 256) {
    int a = i >> 5, gg = i & 31;
    ushort4 v4 = *reinterpret_cast<const ushort4*>(kvb + a * 256 + 128 + 4 * gg);
    Vs[a][4 * gg + 0] = bfus2(v4.x); Vs[a][4 * gg + 1] = bfus2(v4.y);
    Vs[a][4 * gg + 2] = bfus2(v4.z); Vs[a][4 * gg + 3] = bfus2(v4.w);
  }
  __syncthreads();

  const int w = t >> 6, l = t & 63;
  const int qq = 4 * quad + w;
  const float scale = 0.08838834764831845f;

  const float* q0p = qbase + (size_t)(4 * qq + 0) * 128;
  const float* q1p = qbase + (size_t)(4 * qq + 1) * 128;
  const float* q2p = qbase + (size_t)(4 * qq + 2) * 128;
  const float* q3p = qbase + (size_t)(4 * qq + 3) * 128;
  float s0 = 0.f, s1 = 0.f, s2 = 0.f, s3 = 0.f;
  #pragma unroll 8
  for (int i = 0; i < 32; ++i) {
    float4 k = Ks4[l * 32 + (i ^ (l & 7))];
    float4 q0 = *reinterpret_cast<const float4*>(q0p + 4 * i);
    float4 q1 = *reinterpret_cast<const float4*>(q1p + 4 * i);
    float4 q2 = *reinterpret_cast<const float4*>(q2p + 4 * i);
    float4 q3 = *reinterpret_cast<const float4*>(q3p + 4 * i);
    s0 += q0.x * k.x + q0.y * k.y + q0.z * k.z + q0.w * k.w;
    s1 += q1.x * k.x + q1.y * k.y + q1.z * k.z + q1.w * k.w;
    s2 += q2.x * k.x + q2.y * k.y + q2.z * k.z + q2.w * k.w;
    s3 += q3.x * k.x + q3.y * k.y + q3.z * k.z + q3.w * k.w;
  }
  s0 *= scale; s1 *= scale; s2 *= scale; s3 *= scale;

  float p0 = __expf(s0 - wave_max64(s0));
  float p1 = __expf(s1 - wave_max64(s1));
  float p2 = __expf(s2 - wave_max64(s2));
  float p3 = __expf(s3 - wave_max64(s3));
  p0 /= wave_sum64(p0); p1 /= wave_sum64(p1);
  p2 /= wave_sum64(p2); p3 /= wave_sum64(p3);

  Ps[w][0][l] = p0; Ps[w][1][l] = p1; Ps[w][2][l] = p2; Ps[w][3][l] = p3;
  __threadfence_block();

  float a00 = 0.f, a01 = 0.f, a10 = 0.f, a11 = 0.f;
  float a20 = 0.f, a21 = 0.f, a30 = 0.f, a31 = 0.f;
  for (int a = 0; a < 64; ++a) {
    float2 v = *reinterpret_cast<const float2*>(&Vs[a][2 * l]);
    float pa0 = Ps[w][0][a], pa1 = Ps[w][1][a];
    float pa2 = Ps[w][2][a], pa3 = Ps[w][3][a];
    a00 += pa0 * v.x; a01 += pa0 * v.y;
    a10 += pa1 * v.x; a11 += pa1 * v.y;
    a20 += pa2 * v.x; a21 += pa2 * v.y;
    a30 += pa3 * v.x; a31 += pa3 * v.y;
  }
  size_t row0 = (size_t)(b * APG + 4 * qq) * FEAT + 2 * l;
  float2* o0 = reinterpret_cast<float2*>(out_s + row0);
  float2* o1 = reinterpret_cast<float2*>(out_s + row0 + FEAT);
  float2* o2 = reinterpret_cast<float2*>(out_s + row0 + 2 * FEAT);
  float2* o3 = reinterpret_cast<float2*>(out_s + row0 + 3 * FEAT);
  float2 c0 = *o0; c0.x += a00; c0.y += a01; *o0 = c0;
  float2 c1 = *o1; c1.x += a10; c1.y += a11; *o1 = c1;
  float2 c2 = *o2; c2.x += a20; c2.y += a21; *o2 = c2;
  float2 c3 = *o3; c3.x += a30; c3.y += a31; *o3 = c3;
}

// ---------------------------------------------------------------- launch
extern "C" void kernel_launch(void* const* d_in, const int* in_sizes, int n_in,
                              void* d_out, int out_size, void* d_ws, size_t ws_size,
                              hipStream_t stream) {
  const float* s_j  = (const float*)d_in[0];
  const float* v_j  = (const float*)d_in[1];
  const float* r_ij = (const float*)d_in[2];
  const int*   nbrs = (const int*)d_in[3];
  const float* W1   = (const float*)d_in[5];
  const float* b1   = (const float*)d_in[6];
  const float* W2   = (const float*)d_in[7];
  const float* b2   = (const float*)d_in[8];
  const float* Wr   = (const float*)d_in[9];
  const float* br   = (const float*)d_in[10];
  const float* Wd   = (const float*)d_in[11];
  const float* bd   = (const float*)d_in[12];

  float* out_s = (float*)d_out;
  float* out_v = out_s + (size_t)NATOMS * FEAT;

  // workspace ~25 MB (<= 26.4 proven).
  float*    Qf   = (float*)d_ws;                         // 4 MB
  ushort_t* kvbf = (ushort_t*)(Qf + NATOMS * FEAT);      // 4 MB
  ushort_t* PV   = kvbf + (size_t)NATOMS * 256;          // 4 x 3.15 MB quarter tables
  ushort_t* w1s  = PV + 4 * QTUS;                        // 16384
  ushort_t* w2s  = w1s + 16384;                          // 49152
  ushort_t* wds  = w2s + 49152;                          // 49152
  ushort_t* wrs  = wds + 49152;                          // 12288
  uint4*    erec = (uint4*)(wrs + 12288);                // 4 MB
  int* offs   = (int*)(erec + NEDGES);                   // NATOMS+1
  int* cursor = offs + (NATOMS + 1);
  int* counts = cursor + NATOMS;

  hipMemsetAsync(counts, 0, NATOMS * sizeof(int), stream);

  int prep_total = NATOMS * FEAT + 16384 + 49152 + 49152 + 12288 + NEDGES;
  prep_kernel<<<(prep_total + 255) / 256, 256, 0, stream>>>(
      v_j, W1, W2, Wd, Wr, br, nbrs, PV, w1s, w2s, wds, wrs, counts);

  scan_kernel<<<1, 1024, 0, stream>>>(counts, offs, cursor);
  scatter_kernel<<<NEDGES / 256, 256, 0, stream>>>(nbrs, r_ij, cursor, erec);

  gemm_big<<<dim3(NATOMS / 64, 6), 256, 0, stream>>>(
      s_j, w1s, b1, w2s, b2, wds, bd, PV, Qf, kvbf);

  edge_mfma12<<<NATOMS / APW, 256, 0, stream>>>(erec, offs, PV, wrs, out_s, out_v);
  attn_kernel<<<NGRAPH * 4, 256, 0, stream>>>(Qf, kvbf, out_s);
}

// Round 20
// 129.157 us; speedup vs baseline: 1.2471x; 1.2471x over previous
//
#include <hip/hip_runtime.h>
#include <hip/hip_bf16.h>
#include <cstdint>

#define FEAT    128
#define NRBF    20
#define NATOMS  8192
#define NEDGES  262144
#define NGRAPH  128
#define APG     64
#define PI_F    3.14159265358979323846f
#define CUTOFF_F 5.0f
#define QTUS    ((size_t)NATOMS * 32 * 6)   // ushorts per PV quarter-table (3.15 MB)
#define APW     2                           // atoms per wave (edge kernel)

typedef unsigned int uint_t;
typedef unsigned short ushort_t;
typedef __attribute__((ext_vector_type(4))) float f32x4;
typedef __attribute__((ext_vector_type(4))) short short4v;
typedef __attribute__((ext_vector_type(8))) short short8;
struct U3 { uint_t x, y, z; };   // 12 B -> global_load_dwordx3

__device__ __forceinline__ float bflo(uint_t u) { return __uint_as_float(u << 16); }
__device__ __forceinline__ float bfhi(uint_t u) { return __uint_as_float(u & 0xffff0000u); }
__device__ __forceinline__ ushort_t f2bf(float f) {
  uint_t u = __float_as_uint(f);
  return (ushort_t)((u + 0x7fffu + ((u >> 16) & 1u)) >> 16);
}
__device__ __forceinline__ uint_t pack2(float lo, float hi) {
  return (uint_t)f2bf(lo) | ((uint_t)f2bf(hi) << 16);
}

// ---------------------------------------------------------------- prep (+hist fused)
__device__ __forceinline__ ushort_t swz_elem(const float* __restrict__ W, int N,
                                             int NT, int i) {
  int jj = i & 7, lane = (i >> 3) & 63, tile = i >> 9;
  int ks = tile / NT, ctg = tile - ks * NT;
  int g = lane >> 4, q = lane & 15;
  int k = 32 * ks + 4 * g + (jj & 3) + 16 * (jj >> 2);
  int c = 16 * ctg + q;
  return f2bf(W[(size_t)k * N + c]);
}

__global__ void prep_kernel(const float* __restrict__ v_j, const float* __restrict__ W1,
                            const float* __restrict__ W2, const float* __restrict__ Wd,
                            const float* __restrict__ Wr, const float* __restrict__ br,
                            const int* __restrict__ nbrs,
                            ushort_t* __restrict__ PV, ushort_t* __restrict__ w1s,
                            ushort_t* __restrict__ w2s, ushort_t* __restrict__ wds,
                            ushort_t* __restrict__ wrs, int* __restrict__ counts) {
  int i = blockIdx.x * 256 + threadIdx.x;
  if (i < NATOMS * FEAT) {                 // i = j*128 + f
    int j = i >> 7, f = i & 127;
    int tbl = f >> 5, fl = f & 31;
    const float* vp = v_j + (size_t)i * 3; // v_j[j][f][0..2]
    uint_t* o = reinterpret_cast<uint_t*>(PV + (size_t)tbl * QTUS + ((size_t)j * 32 + fl) * 6);
    o[0] = 0u;                     // p0,p1 (gemm fills)
    o[1] = pack2(0.f, vp[0]);      // p2,v0
    o[2] = pack2(vp[1], vp[2]);    // v1,v2
    return;
  }
  i -= NATOMS * FEAT;
  if (i < 16384) { w1s[i] = swz_elem(W1, 128, 8, i); return; }
  i -= 16384;
  if (i < 49152) { w2s[i] = swz_elem(W2, 384, 24, i); return; }
  i -= 49152;
  if (i < 49152) { wds[i] = swz_elem(Wd, 384, 24, i); return; }
  i -= 49152;
  if (i < 12288) {                 // Wr/br frag-order: 24 tiles, k=20 row is br
    int jj = i & 7, lane = (i >> 3) & 63, ct = i >> 9;
    int g = lane >> 4, q = lane & 15;
    int k = 4 * g + (jj & 3) + 16 * (jj >> 2);
    int f = 16 * ct + q;
    float v = (k < NRBF) ? Wr[k * 384 + f] : (k == NRBF ? br[f] : 0.f);
    wrs[i] = f2bf(v);
    return;
  }
  i -= 12288;
  if (i < NEDGES) atomicAdd(&counts[nbrs[2 * i]], 1);   // fused histogram
}

// ---------------------------------------------------------------- big GEMM
// Grid (128, 6): per block stage s_j tile once; emit qkv slice y AND phi slice y
// (h recomputed into Buf). Fragment maps HW-verified (rounds 3-18).
__global__ __launch_bounds__(256) void gemm_big(
    const float* __restrict__ s_j, const ushort_t* __restrict__ w1s,
    const float* __restrict__ b1, const ushort_t* __restrict__ w2s,
    const float* __restrict__ b2, const ushort_t* __restrict__ wds,
    const float* __restrict__ bd, ushort_t* __restrict__ PV,
    float* __restrict__ Qf, ushort_t* __restrict__ kvbf) {
  __shared__ ushort_t Buf[64][136];
  const int t = threadIdx.x;
  const int r0 = blockIdx.x * 64;
  const int y = blockIdx.y;                // 0..5
  const int w = t >> 6, l = t & 63, g = l >> 4, q = l & 15;

  for (int i = t; i < 64 * 32; i += 256) {
    int r = i >> 5, k4 = i & 31;
    float4 v = *reinterpret_cast<const float4*>(s_j + (size_t)(r0 + r) * 128 + 4 * k4);
    ushort4 o = {f2bf(v.x), f2bf(v.y), f2bf(v.z), f2bf(v.w)};
    *reinterpret_cast<ushort4*>(&Buf[r][4 * k4]) = o;
  }
  __syncthreads();

  short8 afr[4];
  #pragma unroll
  for (int ks = 0; ks < 4; ++ks) {
    const ushort_t* ap = &Buf[16 * w + q][32 * ks + 4 * g];
    short4v alo = *reinterpret_cast<const short4v*>(ap);
    short4v ahi = *reinterpret_cast<const short4v*>(ap + 16);
    afr[ks] = short8{alo[0], alo[1], alo[2], alo[3], ahi[0], ahi[1], ahi[2], ahi[3]};
  }
  __syncthreads();   // all Buf reads done before the h overwrite below

  // ---- qkv slice y
  #pragma unroll
  for (int ct = 0; ct < 4; ++ct) {
    f32x4 acc = {};
    #pragma unroll
    for (int ks = 0; ks < 4; ++ks) {
      short8 bf = *reinterpret_cast<const short8*>(
          wds + ((size_t)(ks * 24 + y * 4 + ct) * 64 + l) * 8);
      acc = __builtin_amdgcn_mfma_f32_16x16x32_bf16(afr[ks], bf, acc, 0, 0, 0);
    }
    int col = y * 64 + 16 * ct + q;
    float bb = bd[col];
    #pragma unroll
    for (int r = 0; r < 4; ++r) {
      float o = acc[r] + bb;
      int row = r0 + 16 * w + 4 * g + r;
      if (col < 128) Qf[(size_t)row * 128 + col] = o;
      else           kvbf[(size_t)row * 256 + col - 128] = f2bf(o);
    }
  }

  // ---- h = silu(s@W1+b1) into Buf
  #pragma unroll
  for (int ct = 0; ct < 8; ++ct) {
    f32x4 acc = {};
    #pragma unroll
    for (int ks = 0; ks < 4; ++ks) {
      short8 bf = *reinterpret_cast<const short8*>(
          w1s + ((size_t)(ks * 8 + ct) * 64 + l) * 8);
      acc = __builtin_amdgcn_mfma_f32_16x16x32_bf16(afr[ks], bf, acc, 0, 0, 0);
    }
    float bb = b1[16 * ct + q];
    #pragma unroll
    for (int r = 0; r < 4; ++r) {
      float o = acc[r] + bb;
      o = o / (1.f + __expf(-o));
      Buf[16 * w + 4 * g + r][16 * ct + q] = f2bf(o);
    }
  }
  __syncthreads();

  // ---- phi slice y from Buf
  short8 hfr[4];
  #pragma unroll
  for (int ks = 0; ks < 4; ++ks) {
    const ushort_t* ap = &Buf[16 * w + q][32 * ks + 4 * g];
    short4v alo = *reinterpret_cast<const short4v*>(ap);
    short4v ahi = *reinterpret_cast<const short4v*>(ap + 16);
    hfr[ks] = short8{alo[0], alo[1], alo[2], alo[3], ahi[0], ahi[1], ahi[2], ahi[3]};
  }
  #pragma unroll
  for (int ct = 0; ct < 4; ++ct) {
    f32x4 acc = {};
    #pragma unroll
    for (int ks = 0; ks < 4; ++ks) {
      short8 bf = *reinterpret_cast<const short8*>(
          w2s + ((size_t)(ks * 24 + y * 4 + ct) * 64 + l) * 8);
      acc = __builtin_amdgcn_mfma_f32_16x16x32_bf16(hfr[ks], bf, acc, 0, 0, 0);
    }
    int col = y * 64 + 16 * ct + q;
    float bb = b2[col];
    int f = col & 127, s = col >> 7;
    int tbl = f >> 5, fl = f & 31;
    #pragma unroll
    for (int r = 0; r < 4; ++r) {
      float o = acc[r] + bb;
      int row = r0 + 16 * w + 4 * g + r;
      PV[(size_t)tbl * QTUS + ((size_t)row * 32 + fl) * 6 + s] = f2bf(o);
    }
  }
}

// ---------------------------------------------------------------- sort helpers
__global__ __launch_bounds__(1024) void scan_kernel(
    const int* __restrict__ counts, int* __restrict__ offs, int* __restrict__ cursor) {
  __shared__ int part[1024];
  const int t = threadIdx.x;
  int local[8];
  int s = 0;
  #pragma unroll
  for (int i = 0; i < 8; ++i) { local[i] = counts[t * 8 + i]; s += local[i]; }
  part[t] = s;
  __syncthreads();
  for (int off = 1; off < 1024; off <<= 1) {
    int v = part[t];
    int add = (t >= off) ? part[t - off] : 0;
    __syncthreads();
    part[t] = v + add;
    __syncthreads();
  }
  int excl = part[t] - s;
  #pragma unroll
  for (int i = 0; i < 8; ++i) {
    offs[t * 8 + i] = excl;
    cursor[t * 8 + i] = excl;
    excl += local[i];
  }
  if (t == 1023) offs[NATOMS] = excl;
}

// Pre-joined 16 B edge records {j, x, y, z} in sorted (dest-atom) order.
__global__ void scatter_kernel(const int* __restrict__ nbrs, const float* __restrict__ r_ij,
                               int* __restrict__ cursor, uint4* __restrict__ erec) {
  int e = blockIdx.x * blockDim.x + threadIdx.x;
  if (e < NEDGES) {
    int2 nb = *reinterpret_cast<const int2*>(nbrs + 2 * e);
    int pos = atomicAdd(&cursor[nb.x], 1);
    const float* rp = r_ij + 3 * e;
    erec[pos] = make_uint4((uint_t)nb.y, __float_as_uint(rp[0]),
                           __float_as_uint(rp[1]), __float_as_uint(rp[2]));
  }
}

// ---------------------------------------------------------------- edge MFMA v9 (best)
// APW=2 atoms per wave (one quarter each), 4096 blocks x 4 waves = 16384 waves.
// Zero LDS; B-frags in registers; on-the-fly trig (overlaps gather latency --
// r16/r17/r19 proved both trimming it and pipelining around it expose stalls);
// float shuffles for row metadata. qtr = bid&3 keeps the L2-capacity-fit XCD map.
// C map HW-verified: row = 4g+reg = edge, col = q.
__global__ __launch_bounds__(256) void edge_mfma9(
    const uint4* __restrict__ erec, const int* __restrict__ offs,
    const ushort_t* __restrict__ PV, const ushort_t* __restrict__ wrs,
    float* __restrict__ out_s, float* __restrict__ out_v) {
  const int t = threadIdx.x;
  const int qtr = blockIdx.x & 3;
  const int w = t >> 6, l = t & 63, g = l >> 4, q = l & 15;

  // loop-invariant B-frags: [section][ct]
  short8 Bf[3][2];
  #pragma unroll
  for (int s = 0; s < 3; ++s)
    #pragma unroll
    for (int c = 0; c < 2; ++c)
      Bf[s][c] = *reinterpret_cast<const short8*>(
          wrs + ((size_t)(s * 8 + 2 * qtr + c) * 64 + l) * 8);

  const int a0 = ((blockIdx.x >> 2) * 4 + w) * APW;
  const float c1 = PI_F / CUTOFF_F;
  const char* PVb = reinterpret_cast<const char*>(PV) + (size_t)qtr * QTUS * 2;

  int eb = offs[a0];
  int end = offs[a0 + 1];
  uint4 er = make_uint4(0u, 0u, 0u, 0u);
  if (eb + q < end) er = erec[eb + q];

  for (int aidx = 0; aidx < APW; ++aidx) {
    const int end_next = (aidx + 1 < APW) ? offs[a0 + aidx + 2] : 0;
    float ds0 = 0.f, ds1 = 0.f;
    float dv[2][3] = {};

    for (;;) {
      const bool last = (eb + 16 >= end);
      const int neb = last ? end : (eb + 16);
      const int nend = last ? ((aidx + 1 < APW) ? end_next : neb) : end;
      uint4 ern = make_uint4(0u, 0u, 0u, 0u);
      if (neb + q < nend) ern = erec[neb + q];

      // ---- metadata from pre-joined record (lane q owns edge eb+q)
      float ang = 0.f, ie = 0.f, env = 0.f, u0 = 0.f, u1 = 0.f, u2 = 0.f;
      int jn = 0;
      if (eb + q < end) {
        jn = (int)er.x;
        float x = __uint_as_float(er.y), y = __uint_as_float(er.z), z = __uint_as_float(er.w);
        float d = sqrtf(x * x + y * y + z * z);
        float inv = 1.f / d;
        ang = c1 * d;
        env = (d < CUTOFF_F) ? 0.5f * (__cosf(ang) + 1.f) : 0.f;
        ie = inv * env;
        u0 = x * inv; u1 = y * inv; u2 = z * inv;
      }
      // ---- row (edge eb+4g+r) metadata broadcast + base pointers
      const char* pb[4];
      float ub[4][3];
      #pragma unroll
      for (int r = 0; r < 4; ++r) {
        int src = 4 * g + r;
        int jr = __shfl(jn, src, 64);
        ub[r][0] = __shfl(u0, src, 64);
        ub[r][1] = __shfl(u1, src, 64);
        ub[r][2] = __shfl(u2, src, 64);
        pb[r] = PVb + (size_t)jr * 384 + (size_t)q * 12;
      }
      // ---- 8 PV gathers (12 B each) up front
      U3 ld[2][4];
      #pragma unroll
      for (int c = 0; c < 2; ++c)
        #pragma unroll
        for (int r = 0; r < 4; ++r)
          ld[c][r] = *reinterpret_cast<const U3*>(pb[r] + (size_t)c * 192);
      // ---- A fragment: k = kmap(g,jj) = 4g+(jj&3)+16*(jj>>2)
      short8 af;
      #pragma unroll
      for (int jj = 0; jj < 8; ++jj) {
        int k = 4 * g + (jj & 3) + 16 * (jj >> 2);
        float v = (k < NRBF) ? ie * __sinf((float)(k + 1) * ang)
                             : (k == NRBF ? env : 0.f);
        af[jj] = (short)f2bf(v);
      }
      // ---- 2 col-tiles x 3 sections
      #pragma unroll
      for (int c = 0; c < 2; ++c) {
        f32x4 z4 = {0.f, 0.f, 0.f, 0.f};
        f32x4 cs0 = __builtin_amdgcn_mfma_f32_16x16x32_bf16(af, Bf[0][c], z4, 0, 0, 0);
        f32x4 cs1 = __builtin_amdgcn_mfma_f32_16x16x32_bf16(af, Bf[1][c], z4, 0, 0, 0);
        f32x4 cs2 = __builtin_amdgcn_mfma_f32_16x16x32_bf16(af, Bf[2][c], z4, 0, 0, 0);
        #pragma unroll
        for (int r = 0; r < 4; ++r) {
          U3 u = ld[c][r];
          float p0 = bflo(u.x), p1 = bfhi(u.x);
          float p2 = bflo(u.y), v0 = bfhi(u.y);
          float v1 = bflo(u.z), v2 = bfhi(u.z);
          float pw0 = p0 * cs0[r];
          if (c == 0) ds0 += p1 * cs1[r]; else ds1 += p1 * cs1[r];
          float pw2 = p2 * cs2[r];
          dv[c][0] += pw0 * v0 + pw2 * ub[r][0];
          dv[c][1] += pw0 * v1 + pw2 * ub[r][1];
          dv[c][2] += pw0 * v2 + pw2 * ub[r][2];
        }
      }
      er = ern;
      eb = neb;
      if (last) break;
    }

    // ---- reduce the 4 g-copies and write atom a0+aidx
    float r0v = ds0, r1v = ds1;
    r0v += __shfl_xor(r0v, 16, 64); r0v += __shfl_xor(r0v, 32, 64);
    r1v += __shfl_xor(r1v, 16, 64); r1v += __shfl_xor(r1v, 32, 64);
    float dvr[2][3];
    #pragma unroll
    for (int c = 0; c < 2; ++c)
      #pragma unroll
      for (int cc = 0; cc < 3; ++cc) {
        float y = dv[c][cc];
        y += __shfl_xor(y, 16, 64); y += __shfl_xor(y, 32, 64);
        dvr[c][cc] = y;
      }
    if (g < 2) {
      int atom = a0 + aidx;
      float sv = (g == 0) ? r0v : r1v;
      float d0 = (g == 0) ? dvr[0][0] : dvr[1][0];
      float d1 = (g == 0) ? dvr[0][1] : dvr[1][1];
      float d2 = (g == 0) ? dvr[0][2] : dvr[1][2];
      int f = 32 * qtr + 16 * g + q;
      out_s[(size_t)atom * FEAT + f] = sv;
      float* ov = out_v + (size_t)atom * 384 + (size_t)f * 3;
      ov[0] = d0; ov[1] = d1; ov[2] = d2;
    }
    end = end_next;
  }
}

// ---------------------------------------------------------------- attention
__device__ __forceinline__ float wave_max64(float v) {
  #pragma unroll
  for (int m = 32; m > 0; m >>= 1) v = fmaxf(v, __shfl_xor(v, m, 64));
  return v;
}
__device__ __forceinline__ float wave_sum64(float v) {
  #pragma unroll
  for (int m = 32; m > 0; m >>= 1) v += __shfl_xor(v, m, 64);
  return v;
}
__device__ __forceinline__ float bfus2(ushort_t u) { return __uint_as_float((uint_t)u << 16); }

// 4 blocks per graph (quad = bid&3); each wave handles one group of 4 queries.
__global__ __launch_bounds__(256) void attn_kernel(const float* __restrict__ Qf,
                                                   const ushort_t* __restrict__ kvbf,
                                                   float* __restrict__ out_s) {
  __shared__ float4 Ks4[64 * 32];
  __shared__ float  Vs[64][130];
  __shared__ float  Ps[4][4][64];
  const int b = blockIdx.x >> 2, quad = blockIdx.x & 3;
  const int t = threadIdx.x;
  const float* qbase = Qf + (size_t)b * APG * 128;
  const ushort_t* kvb = kvbf + (size_t)b * APG * 256;

  for (int i = t; i < 64 * 32; i += 256) {
    int a = i >> 5, gg = i & 31;
    ushort4 k4 = *reinterpret_cast<const ushort4*>(kvb + a * 256 + 4 * gg);
    float4 kf = {bfus2(k4.x), bfus2(k4.y), bfus2(k4.z), bfus2(k4.w)};
    Ks4[a * 32 + (gg ^ (a & 7))] = kf;
  }
  for (int i = t; i < 64 * 32; i += 256) {
    int a = i >> 5, gg = i & 31;
    ushort4 v4 = *reinterpret_cast<const ushort4*>(kvb + a * 256 + 128 + 4 * gg);
    Vs[a][4 * gg + 0] = bfus2(v4.x); Vs[a][4 * gg + 1] = bfus2(v4.y);
    Vs[a][4 * gg + 2] = bfus2(v4.z); Vs[a][4 * gg + 3] = bfus2(v4.w);
  }
  __syncthreads();

  const int w = t >> 6, l = t & 63;
  const int qq = 4 * quad + w;
  const float scale = 0.08838834764831845f;

  const float* q0p = qbase + (size_t)(4 * qq + 0) * 128;
  const float* q1p = qbase + (size_t)(4 * qq + 1) * 128;
  const float* q2p = qbase + (size_t)(4 * qq + 2) * 128;
  const float* q3p = qbase + (size_t)(4 * qq + 3) * 128;
  float s0 = 0.f, s1 = 0.f, s2 = 0.f, s3 = 0.f;
  #pragma unroll 8
  for (int i = 0; i < 32; ++i) {
    float4 k = Ks4[l * 32 + (i ^ (l & 7))];
    float4 q0 = *reinterpret_cast<const float4*>(q0p + 4 * i);
    float4 q1 = *reinterpret_cast<const float4*>(q1p + 4 * i);
    float4 q2 = *reinterpret_cast<const float4*>(q2p + 4 * i);
    float4 q3 = *reinterpret_cast<const float4*>(q3p + 4 * i);
    s0 += q0.x * k.x + q0.y * k.y + q0.z * k.z + q0.w * k.w;
    s1 += q1.x * k.x + q1.y * k.y + q1.z * k.z + q1.w * k.w;
    s2 += q2.x * k.x + q2.y * k.y + q2.z * k.z + q2.w * k.w;
    s3 += q3.x * k.x + q3.y * k.y + q3.z * k.z + q3.w * k.w;
  }
  s0 *= scale; s1 *= scale; s2 *= scale; s3 *= scale;

  float p0 = __expf(s0 - wave_max64(s0));
  float p1 = __expf(s1 - wave_max64(s1));
  float p2 = __expf(s2 - wave_max64(s2));
  float p3 = __expf(s3 - wave_max64(s3));
  p0 /= wave_sum64(p0); p1 /= wave_sum64(p1);
  p2 /= wave_sum64(p2); p3 /= wave_sum64(p3);

  Ps[w][0][l] = p0; Ps[w][1][l] = p1; Ps[w][2][l] = p2; Ps[w][3][l] = p3;
  __threadfence_block();

  float a00 = 0.f, a01 = 0.f, a10 = 0.f, a11 = 0.f;
  float a20 = 0.f, a21 = 0.f, a30 = 0.f, a31 = 0.f;
  for (int a = 0; a < 64; ++a) {
    float2 v = *reinterpret_cast<const float2*>(&Vs[a][2 * l]);
    float pa0 = Ps[w][0][a], pa1 = Ps[w][1][a];
    float pa2 = Ps[w][2][a], pa3 = Ps[w][3][a];
    a00 += pa0 * v.x; a01 += pa0 * v.y;
    a10 += pa1 * v.x; a11 += pa1 * v.y;
    a20 += pa2 * v.x; a21 += pa2 * v.y;
    a30 += pa3 * v.x; a31 += pa3 * v.y;
  }
  size_t row0 = (size_t)(b * APG + 4 * qq) * FEAT + 2 * l;
  float2* o0 = reinterpret_cast<float2*>(out_s + row0);
  float2* o1 = reinterpret_cast<float2*>(out_s + row0 + FEAT);
  float2* o2 = reinterpret_cast<float2*>(out_s + row0 + 2 * FEAT);
  float2* o3 = reinterpret_cast<float2*>(out_s + row0 + 3 * FEAT);
  float2 c0 = *o0; c0.x += a00; c0.y += a01; *o0 = c0;
  float2 c1 = *o1; c1.x += a10; c1.y += a11; *o1 = c1;
  float2 c2 = *o2; c2.x += a20; c2.y += a21; *o2 = c2;
  float2 c3 = *o3; c3.x += a30; c3.y += a31; *o3 = c3;
}

// ---------------------------------------------------------------- launch
extern "C" void kernel_launch(void* const* d_in, const int* in_sizes, int n_in,
                              void* d_out, int out_size, void* d_ws, size_t ws_size,
                              hipStream_t stream) {
  const float* s_j  = (const float*)d_in[0];
  const float* v_j  = (const float*)d_in[1];
  const float* r_ij = (const float*)d_in[2];
  const int*   nbrs = (const int*)d_in[3];
  const float* W1   = (const float*)d_in[5];
  const float* b1   = (const float*)d_in[6];
  const float* W2   = (const float*)d_in[7];
  const float* b2   = (const float*)d_in[8];
  const float* Wr   = (const float*)d_in[9];
  const float* br   = (const float*)d_in[10];
  const float* Wd   = (const float*)d_in[11];
  const float* bd   = (const float*)d_in[12];

  float* out_s = (float*)d_out;
  float* out_v = out_s + (size_t)NATOMS * FEAT;

  // workspace ~25 MB (<= 26.4 proven).
  float*    Qf   = (float*)d_ws;                         // 4 MB
  ushort_t* kvbf = (ushort_t*)(Qf + NATOMS * FEAT);      // 4 MB
  ushort_t* PV   = kvbf + (size_t)NATOMS * 256;          // 4 x 3.15 MB quarter tables
  ushort_t* w1s  = PV + 4 * QTUS;                        // 16384
  ushort_t* w2s  = w1s + 16384;                          // 49152
  ushort_t* wds  = w2s + 49152;                          // 49152
  ushort_t* wrs  = wds + 49152;                          // 12288
  uint4*    erec = (uint4*)(wrs + 12288);                // 4 MB
  int* offs   = (int*)(erec + NEDGES);                   // NATOMS+1
  int* cursor = offs + (NATOMS + 1);
  int* counts = cursor + NATOMS;

  hipMemsetAsync(counts, 0, NATOMS * sizeof(int), stream);

  int prep_total = NATOMS * FEAT + 16384 + 49152 + 49152 + 12288 + NEDGES;
  prep_kernel<<<(prep_total + 255) / 256, 256, 0, stream>>>(
      v_j, W1, W2, Wd, Wr, br, nbrs, PV, w1s, w2s, wds, wrs, counts);

  scan_kernel<<<1, 1024, 0, stream>>>(counts, offs, cursor);
  scatter_kernel<<<NEDGES / 256, 256, 0, stream>>>(nbrs, r_ij, cursor, erec);

  gemm_big<<<dim3(NATOMS / 64, 6), 256, 0, stream>>>(
      s_j, w1s, b1, w2s, b2, wds, bd, PV, Qf, kvbf);

  edge_mfma9<<<NATOMS / APW, 256, 0, stream>>>(erec, offs, PV, wrs, out_s, out_v);
  attn_kernel<<<NGRAPH * 4, 256, 0, stream>>>(Qf, kvbf, out_s);
}